// Round 10
// baseline (37.871 us; speedup 1.0000x reference)
//
#include <hip/hip_runtime.h>

#define NOUT 10
#define SIG_DIM 584   // 8 + 64 + 512
#define TPAD 17       // col bank stride 17: banks {17c+t}%32 distinct per c
#define TPAD2 132     // fallback kernel's pad

typedef float float8v __attribute__((ext_vector_type(8)));

__device__ __forceinline__ float rdlane(float x, int lane) {
    return __int_as_float(__builtin_amdgcn_readlane(__float_as_int(x), lane));
}

// ---- Prepass: dX = X[t+1]-X[t] (row 127 zeroed) into d_ws, coalesced. ----
__global__ __launch_bounds__(256) void dx_prepass(const float* __restrict__ X,
                                                  float* __restrict__ dX)
{
    const int t = blockIdx.x * 256 + threadIdx.x;   // float4 index, 524288 total
    const int r = (t >> 1) & 127;                   // row within batch
    const float4* X4 = reinterpret_cast<const float4*>(X);
    const float4 a = X4[t];
    float4 d = make_float4(0.f, 0.f, 0.f, 0.f);
    if (r < 127) {
        const float4 c = X4[t + 2];
        d = make_float4(c.x - a.x, c.y - a.y, c.z - a.z, c.w - a.w);
    }
    reinterpret_cast<float4*>(dX)[t] = d;
}

// ---- Main: block = 512 threads = 8 waves = 8 x 16-step chunks of ONE batch.
// 16384 waves total -> 8 waves/SIMD (vs 2 in r1..r8): latency finally hidden.
// Lane l=(i,j). Chunk state: S3[ijk], S2[ij], S1[i], S1[j] (local, from zero).
// Rows: uniform loads from dX via per-wave readfirstlane'd base (scalar-cache
// path if the compiler scalarizes; uniform VMEM otherwise -- both fine at
// 8 waves/SIMD). Cols: transposed LDS, conflict-free, b128 per 4 steps.
// Fold: 3-round LDS tree (8->4->2->regs), ping-pong disjoint buffers,
// __syncthreads between rounds, no early returns. Epilogue split across waves.
__global__ __launch_bounds__(512) void sig_main(
    const float* __restrict__ dX, const float* __restrict__ W,
    const float* __restrict__ bias, float* __restrict__ out)
{
    __shared__ float s_dxT[8][8 * TPAD];     // 4.4 KB
    __shared__ float s_sig[8][SIG_DIM];      // 18.7 KB
    __shared__ float s_sig2[4][SIG_DIM];     // 9.3 KB

    const int tid = threadIdx.x;
    const int w = tid >> 6;          // wave = chunk 0..7
    const int l = tid & 63;
    const int i = l >> 3;
    const int j = l & 7;
    const int b = blockIdx.x;
    const int t0 = w * 16;           // first increment row of this chunk

    const float* dXb = dX + (size_t)b * 1024;

    // Stage this chunk's 16 dX rows transposed into LDS (lanes 0..31).
    if (l < 32) {
        const float4 d = *reinterpret_cast<const float4*>(dXb + t0 * 8 + l * 4);
        float* dt = &s_dxT[w][0];
        const int r = l >> 1, cb = (l & 1) * 4;
        dt[(cb + 0) * TPAD + r] = d.x;
        dt[(cb + 1) * TPAD + r] = d.y;
        dt[(cb + 2) * TPAD + r] = d.z;
        dt[(cb + 3) * TPAD + r] = d.w;
    }
    // Per-wave-uniform row pointer (SGPR-addressed).
    const float8v* srow = reinterpret_cast<const float8v*>(
        dX + (size_t)__builtin_amdgcn_readfirstlane(b * 1024 + t0 * 8));
    __syncthreads();

    float s3[8];
#pragma unroll
    for (int k = 0; k < 8; ++k) s3[k] = 0.f;
    float s2 = 0.f, s1i = 0.f, s1j = 0.f;

    const float* icol = &s_dxT[w][i * TPAD];
    const float* jcol = &s_dxT[w][j * TPAD];

#define STEP(T, DXI, DXJ)                                                     \
    {                                                                         \
        const float8v rr = srow[(T)];                                         \
        const float cc = (DXI) * (DXJ);                                       \
        const float uu = s1i * (DXJ);                                         \
        const float f  = fmaf(0.5f, uu, fmaf(1.0f / 6.0f, cc, s2));           \
        s3[0] = fmaf(f, rr[0], s3[0]);                                        \
        s3[1] = fmaf(f, rr[1], s3[1]);                                        \
        s3[2] = fmaf(f, rr[2], s3[2]);                                        \
        s3[3] = fmaf(f, rr[3], s3[3]);                                        \
        s3[4] = fmaf(f, rr[4], s3[4]);                                        \
        s3[5] = fmaf(f, rr[5], s3[5]);                                        \
        s3[6] = fmaf(f, rr[6], s3[6]);                                        \
        s3[7] = fmaf(f, rr[7], s3[7]);                                        \
        s2 = fmaf(0.5f, cc, s2 + uu);                                         \
        s1i += (DXI);                                                         \
        s1j += (DXJ);                                                         \
    }
#pragma unroll
    for (int g = 0; g < 4; ++g) {
        const float4 ic = *reinterpret_cast<const float4*>(icol + g * 4);
        const float4 jc = *reinterpret_cast<const float4*>(jcol + g * 4);
        STEP(g * 4 + 0, ic.x, jc.x)
        STEP(g * 4 + 1, ic.y, jc.y)
        STEP(g * 4 + 2, ic.z, jc.z)
        STEP(g * 4 + 3, ic.w, jc.w)
    }
#undef STEP

    // sig layout per slot: [0..7]=S1 (lanes i==0 write s1j at [j]),
    // [8+l]=S2[i][j], [72 + k*64 + l]=S3 k-major (stride-1 = conflict-free).
#define PUBLISH(SG)                                                           \
    {                                                                         \
        float* sg_ = (SG);                                                    \
        if (i == 0) sg_[j] = s1j;                                             \
        sg_[8 + l] = s2;                                                      \
        _Pragma("unroll")                                                     \
        for (int k = 0; k < 8; ++k) sg_[72 + k * 64 + l] = s3[k];             \
    }
    // Chen fold of right-sig SG into reg state (left):
    //   S3 += S2a*S1b[k] + S1a[i]*S2b[jk] + S3b;  S2 += S1a[i]*S1b[j] + S2b
#define FOLDF(SG)                                                             \
    {                                                                         \
        const float* sg_ = (SG);                                              \
        const float4 b0 = *reinterpret_cast<const float4*>(sg_);              \
        const float4 b1 = *reinterpret_cast<const float4*>(sg_ + 4);          \
        const float s1bi = sg_[i];                                            \
        const float s1bj = sg_[j];                                            \
        const float s2b = sg_[8 + l];                                         \
        const float4 q0 = *reinterpret_cast<const float4*>(sg_ + 8 + j * 8);  \
        const float4 q1 = *reinterpret_cast<const float4*>(sg_ + 8 + j * 8 + 4); \
        float tb[8];                                                          \
        _Pragma("unroll")                                                     \
        for (int k = 0; k < 8; ++k) tb[k] = sg_[72 + k * 64 + l];             \
        s3[0] = fmaf(s2, b0.x, fmaf(s1i, q0.x, s3[0] + tb[0]));               \
        s3[1] = fmaf(s2, b0.y, fmaf(s1i, q0.y, s3[1] + tb[1]));               \
        s3[2] = fmaf(s2, b0.z, fmaf(s1i, q0.z, s3[2] + tb[2]));               \
        s3[3] = fmaf(s2, b0.w, fmaf(s1i, q0.w, s3[3] + tb[3]));               \
        s3[4] = fmaf(s2, b1.x, fmaf(s1i, q1.x, s3[4] + tb[4]));               \
        s3[5] = fmaf(s2, b1.y, fmaf(s1i, q1.y, s3[5] + tb[5]));               \
        s3[6] = fmaf(s2, b1.z, fmaf(s1i, q1.z, s3[6] + tb[6]));               \
        s3[7] = fmaf(s2, b1.w, fmaf(s1i, q1.w, s3[7] + tb[7]));               \
        s2 = s2 + fmaf(s1i, s1bj, s2b);                                       \
        s1i += s1bi;                                                          \
        s1j += s1bj;                                                          \
    }
#define ZERO_STATE                                                            \
    {                                                                         \
        _Pragma("unroll")                                                     \
        for (int k = 0; k < 8; ++k) s3[k] = 0.f;                              \
        s2 = 0.f; s1i = 0.f; s1j = 0.f;                                       \
    }

    PUBLISH(&s_sig[w][0]);
    __syncthreads();
    // Round 1: waves 0..3 fold chunk pairs (2w, 2w+1) -> s_sig2[w].
    if (w < 4) {
        ZERO_STATE;
        FOLDF(&s_sig[2 * w][0]);
        FOLDF(&s_sig[2 * w + 1][0]);
        PUBLISH(&s_sig2[w][0]);
    }
    __syncthreads();
    // Round 2: waves 0..1 fold (s_sig2[2w], s_sig2[2w+1]) -> s_sig[w].
    if (w < 2) {
        ZERO_STATE;
        FOLDF(&s_sig2[2 * w][0]);
        FOLDF(&s_sig2[2 * w + 1][0]);
        PUBLISH(&s_sig[w][0]);
    }
    __syncthreads();
    // Round 3: ALL waves fold (s_sig[0], s_sig[1]) -> full signature in regs.
    ZERO_STATE;
    FOLDF(&s_sig[0][0]);
    FOLDF(&s_sig[1][0]);
#undef ZERO_STATE
#undef FOLDF
#undef PUBLISH

    // Epilogue: wave w handles o = w, w+8.
    for (int o = w; o < NOUT; o += 8) {
        const float* wrow = W + o * SIG_DIM;
        float part = s2 * wrow[8 + l];
        const float4 w0 = *reinterpret_cast<const float4*>(wrow + 72 + l * 8);
        const float4 w1 = *reinterpret_cast<const float4*>(wrow + 72 + l * 8 + 4);
        part = fmaf(s3[0], w0.x, part); part = fmaf(s3[1], w0.y, part);
        part = fmaf(s3[2], w0.z, part); part = fmaf(s3[3], w0.w, part);
        part = fmaf(s3[4], w1.x, part); part = fmaf(s3[5], w1.y, part);
        part = fmaf(s3[6], w1.z, part); part = fmaf(s3[7], w1.w, part);
        if (i == 0) part = fmaf(s1j, wrow[j], part);   // S1 contribution
#pragma unroll
        for (int off = 32; off > 0; off >>= 1) part += __shfl_xor(part, off);
        if (l == 0) out[b * NOUT + o] = part + bias[o];
    }
}

// ---- Fallback (r5-proven, 21.6 us) if ws_size too small for dX. ----
__global__ __launch_bounds__(256) void sig_fallback(
    const float* __restrict__ X, const float* __restrict__ W,
    const float* __restrict__ bias, float* __restrict__ out)
{
    __shared__ float s_dxT[4][8 * TPAD2];
    const int tid = threadIdx.x;
    const int w = tid >> 6;
    const int l = tid & 63;
    const int i = l >> 3;
    const int j = l & 7;
    const int b = blockIdx.x * 4 + w;
    const float* Xb = X + (size_t)b * 1024;
    float* dxT = &s_dxT[w][0];
    const int cb = (l & 1) * 4;
    const int rl = l >> 1;
    float4 dA, dB, dC, dD;
#define PREP(DQ, QQ)                                                          \
    {                                                                         \
        const int r = (QQ) * 32 + rl;                                         \
        const float* xr = Xb + r * 8 + cb;                                    \
        const float4 a  = *reinterpret_cast<const float4*>(xr);               \
        const float4 c4 = *reinterpret_cast<const float4*>(xr + (r < 127 ? 8 : 0)); \
        DQ.x = (r < 127) ? c4.x - a.x : 0.f;                                  \
        DQ.y = (r < 127) ? c4.y - a.y : 0.f;                                  \
        DQ.z = (r < 127) ? c4.z - a.z : 0.f;                                  \
        DQ.w = (r < 127) ? c4.w - a.w : 0.f;                                  \
        dxT[(cb + 0) * TPAD2 + r] = DQ.x;                                     \
        dxT[(cb + 1) * TPAD2 + r] = DQ.y;                                     \
        dxT[(cb + 2) * TPAD2 + r] = DQ.z;                                     \
        dxT[(cb + 3) * TPAD2 + r] = DQ.w;                                     \
    }
    PREP(dA, 0) PREP(dB, 1) PREP(dC, 2) PREP(dD, 3)
#undef PREP
    __syncthreads();
    float s3[8];
#pragma unroll
    for (int k = 0; k < 8; ++k) s3[k] = 0.f;
    float s2 = 0.f, s1i = 0.f, s1j = 0.f;
    const float* icol = dxT + i * TPAD2;
    const float* jcol = dxT + j * TPAD2;
#define STEP(DQ, LB, DXI, DXJ)                                                \
    {                                                                         \
        const float k0 = rdlane(DQ.x, (LB));                                  \
        const float k1 = rdlane(DQ.y, (LB));                                  \
        const float k2 = rdlane(DQ.z, (LB));                                  \
        const float k3 = rdlane(DQ.w, (LB));                                  \
        const float k4 = rdlane(DQ.x, (LB) + 1);                              \
        const float k5 = rdlane(DQ.y, (LB) + 1);                              \
        const float k6 = rdlane(DQ.z, (LB) + 1);                              \
        const float k7 = rdlane(DQ.w, (LB) + 1);                              \
        const float cc = (DXI) * (DXJ);                                       \
        const float uu = s1i * (DXJ);                                         \
        const float f  = fmaf(0.5f, uu, fmaf(1.0f / 6.0f, cc, s2));           \
        s3[0] = fmaf(f, k0, s3[0]);                                           \
        s3[1] = fmaf(f, k1, s3[1]);                                           \
        s3[2] = fmaf(f, k2, s3[2]);                                           \
        s3[3] = fmaf(f, k3, s3[3]);                                           \
        s3[4] = fmaf(f, k4, s3[4]);                                           \
        s3[5] = fmaf(f, k5, s3[5]);                                           \
        s3[6] = fmaf(f, k6, s3[6]);                                           \
        s3[7] = fmaf(f, k7, s3[7]);                                           \
        s2 = fmaf(0.5f, cc, s2 + uu);                                         \
        s1i += (DXI);                                                         \
        s1j += (DXJ);                                                         \
    }
#define SECTION(DQ, QQ)                                                       \
    for (int g = 0; g < 8; ++g) {                                             \
        const int t0 = (QQ) * 32 + g * 4;                                     \
        const float4 ic = *reinterpret_cast<const float4*>(icol + t0);        \
        const float4 jc = *reinterpret_cast<const float4*>(jcol + t0);        \
        const int lb = g * 8;                                                 \
        STEP(DQ, lb + 0, ic.x, jc.x)                                          \
        STEP(DQ, lb + 2, ic.y, jc.y)                                          \
        STEP(DQ, lb + 4, ic.z, jc.z)                                          \
        STEP(DQ, lb + 6, ic.w, jc.w)                                          \
    }
    SECTION(dA, 0) SECTION(dB, 1) SECTION(dC, 2) SECTION(dD, 3)
#undef SECTION
#undef STEP
#pragma unroll
    for (int o = 0; o < NOUT; ++o) {
        const float* wrow = W + o * SIG_DIM;
        float part = s2 * wrow[8 + l];
        const float4 w0 = *reinterpret_cast<const float4*>(wrow + 72 + l * 8);
        const float4 w1 = *reinterpret_cast<const float4*>(wrow + 72 + l * 8 + 4);
        part = fmaf(s3[0], w0.x, part); part = fmaf(s3[1], w0.y, part);
        part = fmaf(s3[2], w0.z, part); part = fmaf(s3[3], w0.w, part);
        part = fmaf(s3[4], w1.x, part); part = fmaf(s3[5], w1.y, part);
        part = fmaf(s3[6], w1.z, part); part = fmaf(s3[7], w1.w, part);
        if (i == 0) part = fmaf(s1j, wrow[j], part);
#pragma unroll
        for (int off = 32; off > 0; off >>= 1) part += __shfl_xor(part, off);
        if (l == 0) out[b * NOUT + o] = part + bias[o];
    }
}

extern "C" void kernel_launch(void* const* d_in, const int* in_sizes, int n_in,
                              void* d_out, int out_size, void* d_ws, size_t ws_size,
                              hipStream_t stream) {
    const float* X = (const float*)d_in[0];     // (2048, 128, 8)
    const float* W = (const float*)d_in[1];     // (10, 584)
    const float* bias = (const float*)d_in[2];  // (10,)
    float* out = (float*)d_out;                 // (2048, 10)
    const size_t need = 2048ull * 1024ull * sizeof(float);   // 8 MB dX
    if (ws_size >= need) {
        float* dX = (float*)d_ws;
        dx_prepass<<<dim3(2048), dim3(256), 0, stream>>>(X, dX);
        sig_main<<<dim3(2048), dim3(512), 0, stream>>>(dX, W, bias, out);
    } else {
        sig_fallback<<<dim3(512), dim3(256), 0, stream>>>(X, W, bias, out);
    }
}

// Round 11
// 29.694 us; speedup vs baseline: 1.2754x; 1.2754x over previous
//
#include <hip/hip_runtime.h>

#define NOUT 10
#define SIG_DIM 584   // 8 + 64 + 512
#define TPAD 132      // padded T-stride: (c*TPAD)%32 = 4c -> conflict-free cols

__device__ __forceinline__ float rdlane(float x, int lane) {
    return __int_as_float(__builtin_amdgcn_readlane(__float_as_int(x), lane));
}

// k-SPLIT, NO FOLD: 2 waves per batch; BOTH run the full 127-step recurrence
// (redundant s2/s1 state, 7 ops/step), each owns only k-half h*4..h*4+3 of S3
// (4 readlane + 4 fma instead of 8+8). Waves: 4096 -> 4/SIMD (2x r5) with
// ZERO chunk-fold overhead (r6/r9 regressions). Combine = 10-float LDS
// exchange at the end (one barrier, disjoint writes, no early returns).
// Lane l=(i,j): i=l>>3, j=l&7. s1j via closed form X[127]-X[0] (exact).
__global__ __launch_bounds__(256) void sig_linear_kernel(
    const float* __restrict__ X, const float* __restrict__ W,
    const float* __restrict__ bias, float* __restrict__ out)
{
    __shared__ float s_dxT[4][8 * TPAD];   // per-wave transposed dX (16.9 KB)
    __shared__ float s_part[4][16];        // per-wave output partials

    const int tid = threadIdx.x;
    const int w = tid >> 6;
    const int l = tid & 63;
    const int i = l >> 3;
    const int j = l & 7;
    const int h = w & 1;                   // k-half owned by this wave
    const int b = blockIdx.x * 2 + (w >> 1);

    const float* Xb = X + (size_t)b * 1024;
    float* dxT = &s_dxT[w][0];
    const int cb = (l & 1) * 4;            // this lane's 4-col segment
    const int rl = l >> 1;                 // row within 32-row section

    // Prepass (r5-proven): dX rows q*32+rl -> regs dA..dD (readlane source,
    // lane 2s: cols 0-3 = half0, lane 2s+1: cols 4-7 = half1) + transposed
    // LDS columns for per-lane dxi/dxj. Row 127 zeroed. Loads coalesced.
    float4 dA, dB, dC, dD;
#define PREP(DQ, QQ)                                                          \
    {                                                                         \
        const int r = (QQ) * 32 + rl;                                         \
        const float* xr = Xb + r * 8 + cb;                                    \
        const float4 a  = *reinterpret_cast<const float4*>(xr);               \
        const float4 c4 = *reinterpret_cast<const float4*>(xr + (r < 127 ? 8 : 0)); \
        DQ.x = (r < 127) ? c4.x - a.x : 0.f;                                  \
        DQ.y = (r < 127) ? c4.y - a.y : 0.f;                                  \
        DQ.z = (r < 127) ? c4.z - a.z : 0.f;                                  \
        DQ.w = (r < 127) ? c4.w - a.w : 0.f;                                  \
        dxT[(cb + 0) * TPAD + r] = DQ.x;                                      \
        dxT[(cb + 1) * TPAD + r] = DQ.y;                                      \
        dxT[(cb + 2) * TPAD + r] = DQ.z;                                      \
        dxT[(cb + 3) * TPAD + r] = DQ.w;                                      \
    }
    PREP(dA, 0) PREP(dB, 1) PREP(dC, 2) PREP(dD, 3)
#undef PREP
    __syncthreads();   // cross-lane LDS reads below need a real barrier

    float s3[4];
    s3[0] = s3[1] = s3[2] = s3[3] = 0.f;
    float s2 = 0.f, s1i = 0.f;

    const float* icol = dxT + i * TPAD;    // conflict-free: banks 4c+t
    const float* jcol = dxT + j * TPAD;

    // Per-step: 4 rdlane + 4 fma + {cc,uu,f(2),s2(2),s1i} = 15 VALU.
    // dx[h*4+c] of step (section row s) = component c of lane 2s+h.
#define STEP(DQ, LB, DXI, DXJ)                                                \
    {                                                                         \
        const float k0 = rdlane(DQ.x, (LB) + h);                              \
        const float k1 = rdlane(DQ.y, (LB) + h);                              \
        const float k2 = rdlane(DQ.z, (LB) + h);                              \
        const float k3 = rdlane(DQ.w, (LB) + h);                              \
        const float cc = (DXI) * (DXJ);                                       \
        const float uu = s1i * (DXJ);                                         \
        const float f  = fmaf(0.5f, uu, fmaf(1.0f / 6.0f, cc, s2));           \
        s3[0] = fmaf(f, k0, s3[0]);                                           \
        s3[1] = fmaf(f, k1, s3[1]);                                           \
        s3[2] = fmaf(f, k2, s3[2]);                                           \
        s3[3] = fmaf(f, k3, s3[3]);                                           \
        s2 = fmaf(0.5f, cc, s2 + uu);                                         \
        s1i += (DXI);                                                         \
    }

    // One 32-row section: 8 groups of 4 steps; readlane base = g*8 (+h).
#define SECTION(DQ, QQ)                                                       \
    _Pragma("unroll")                                                         \
    for (int g = 0; g < 8; ++g) {                                             \
        const int t0 = (QQ) * 32 + g * 4;                                     \
        const float4 ic = *reinterpret_cast<const float4*>(icol + t0);        \
        const float4 jc = *reinterpret_cast<const float4*>(jcol + t0);        \
        const int lb = g * 8;                                                 \
        STEP(DQ, lb + 0, ic.x, jc.x)                                          \
        STEP(DQ, lb + 2, ic.y, jc.y)                                          \
        STEP(DQ, lb + 4, ic.z, jc.z)                                          \
        STEP(DQ, lb + 6, ic.w, jc.w)                                          \
    }
    SECTION(dA, 0) SECTION(dB, 1) SECTION(dC, 2) SECTION(dD, 3)
#undef SECTION
#undef STEP

    // s1j closed form (telescoping, exact): X[127][j] - X[0][j].
    const float s1j = Xb[127 * 8 + j] - Xb[j];

    // Epilogue: partial dot of this wave's k-half with W; half0 adds S1+S2.
    // sig layout: [0..7]=S1, [8+l]=S2[i][j], [72+l*8+k]=S3[i][j][k].
#pragma unroll
    for (int o = 0; o < NOUT; ++o) {
        const float* wrow = W + o * SIG_DIM;
        const float4 w0 = *reinterpret_cast<const float4*>(wrow + 72 + l * 8 + h * 4);
        float part = fmaf(s3[0], w0.x,
                     fmaf(s3[1], w0.y,
                     fmaf(s3[2], w0.z, s3[3] * w0.w)));
        if (h == 0) {
            part = fmaf(s2, wrow[8 + l], part);
            if (i == 0) part = fmaf(s1j, wrow[j], part);   // S1 contribution
        }
#pragma unroll
        for (int off = 32; off > 0; off >>= 1) part += __shfl_xor(part, off);
        if (l == o) s_part[w][o] = part;   // butterfly leaves total in all lanes
    }
    __syncthreads();

    // Half-0 wave of each pair combines and writes (lane-parallel, 10 lanes).
    if (h == 0 && l < NOUT)
        out[b * NOUT + l] = s_part[w][l] + s_part[w + 1][l] + bias[l];
}

extern "C" void kernel_launch(void* const* d_in, const int* in_sizes, int n_in,
                              void* d_out, int out_size, void* d_ws, size_t ws_size,
                              hipStream_t stream) {
    const float* X = (const float*)d_in[0];     // (2048, 128, 8)
    const float* W = (const float*)d_in[1];     // (10, 584)
    const float* bias = (const float*)d_in[2];  // (10,)
    float* out = (float*)d_out;                 // (2048, 10)
    // 2048 batches x 2 k-half waves = 4096 waves = 1024 blocks of 256.
    sig_linear_kernel<<<dim3(1024), dim3(256), 0, stream>>>(X, W, bias, out);
}

// Round 13
// 26.693 us; speedup vs baseline: 1.4188x; 1.1124x over previous
//
#include <hip/hip_runtime.h>

#define NOUT 10
#define SIG_DIM 584   // 8 + 64 + 512
#define TS 36         // X^T row stride: word (36c+t)%32=(4c+t)%32 -> b128 conflict-free

__device__ __forceinline__ float rdlane(float x, int lane) {
    return __int_as_float(__builtin_amdgcn_readlane(__float_as_int(x), lane));
}
__device__ __forceinline__ float comp4(float4 v, int c) {
    return c == 0 ? v.x : c == 1 ? v.y : c == 2 ? v.z : v.w;
}

// PARALLEL-IN-TIME closed form (no serial recurrence):
//   cp_t = X[t]-X[0];  dx_t = X[t+1]-X[t]
//   g_t[ij] = dx_j*(cp_i + 0.5*dx_i)      == dS2_t[ij]   (S2f = sum_t g_t)
//   h_t[ij] = dx_j*(dx_i/6 + 0.5*cp_i)
//   S3[ijk] = S2f[ij]*X127[k] - sum_t[(g_t-h_t)*X[t+1][k] + h_t*X[t][k]]
// (Abel summation of sum_t S2pre_t[ij] dx_t[k]; S1 = X127-X0, exact.)
// r11 BUG (absmax 187): g had the cross term transposed (dx_i*cp_j); fixed to
// cp_i*dx_j per the serial update  s2 += s1i*dxj + 0.5*dxi*dxj.
// All sums independent over t: block = 1 batch, 4 waves = 4 t-chunks of 32,
// combine additive only (S2f via LDS, outputs via per-wave partial dots).
// 8192 waves -> up to 8/SIMD. Lane l=(i,j). Accum: A[8] (k-dim), S2f.
// Rows X[t][k]: v_readlane of staged regs; cols: transposed LDS, conflict-free.
__global__ __launch_bounds__(256) void sig_linear_kernel(
    const float* __restrict__ X, const float* __restrict__ W,
    const float* __restrict__ bias, float* __restrict__ out)
{
    __shared__ __align__(16) float s_xT[4][8 * TS];  // per-wave X^T (33 rows used)
    __shared__ float s_s2[4][64];
    __shared__ float s_part[4][16];

    const int tid = threadIdx.x;
    const int w = tid >> 6, l = tid & 63, i = l >> 3, j = l & 7;
    const int b = blockIdx.x;
    const int t0 = w * 32;
    const float* Xb = X + (size_t)b * 1024;

    // Stage: lane l holds X row (t0 + (l>>1)), cols cb..cb+3 (readlane source:
    // chunk-row s -> lane 2s (cols 0-3) / 2s+1 (cols 4-7)); also transposed
    // into LDS for per-lane column reads. Row t0+32 staged by lanes 0,1
    // (clamped to 127 for w=3: step 127 then has dx=0 -> contributes 0, exact).
    const int rl_ = l >> 1, cb = (l & 1) * 4;
    const float4 d4 = *reinterpret_cast<const float4*>(Xb + (t0 + rl_) * 8 + cb);
    float* xT = &s_xT[w][0];
    xT[(cb + 0) * TS + rl_] = d4.x;
    xT[(cb + 1) * TS + rl_] = d4.y;
    xT[(cb + 2) * TS + rl_] = d4.z;
    xT[(cb + 3) * TS + rl_] = d4.w;
    if (l < 2) {
        const int rN = (t0 + 32 < 128) ? t0 + 32 : 127;
        const float4 e4 = *reinterpret_cast<const float4*>(Xb + rN * 8 + l * 4);
        xT[(l * 4 + 0) * TS + 32] = e4.x;
        xT[(l * 4 + 1) * TS + 32] = e4.y;
        xT[(l * 4 + 2) * TS + 32] = e4.z;
        xT[(l * 4 + 3) * TS + 32] = e4.w;
    }
    const float x0i = Xb[i];
    const float x0j = Xb[j];
    const float s1jv = Xb[1016 + j] - x0j;   // S1[j], telescoped (exact)
    __syncthreads();

    float A[8];
#pragma unroll
    for (int k = 0; k < 8; ++k) A[k] = 0.f;
    float S2f = 0.f;

    const float* icol = xT + i * TS;
    const float* jcol = xT + j * TS;

    float xcr[8], xnr[8];    // broadcast rows X[t][k] / X[t+1][k]
#pragma unroll
    for (int k = 0; k < 8; ++k)
        xcr[k] = rdlane(comp4(d4, k & 3), k >> 2);        // row t0 (lanes 0,1)

    float4 ic = *reinterpret_cast<const float4*>(icol);
    float4 jc = *reinterpret_cast<const float4*>(jcol);

#pragma unroll
    for (int g4 = 0; g4 < 8; ++g4) {
        float4 in4, jn4;
        if (g4 < 7) {
            in4 = *reinterpret_cast<const float4*>(icol + 4 * g4 + 4);
            jn4 = *reinterpret_cast<const float4*>(jcol + 4 * g4 + 4);
        } else {
            in4 = make_float4(icol[32], 0.f, 0.f, 0.f);
            jn4 = make_float4(jcol[32], 0.f, 0.f, 0.f);
        }
#pragma unroll
        for (int q = 0; q < 4; ++q) {
            const int s = g4 * 4 + q;
            const float xci = comp4(ic, q);
            const float xcj = comp4(jc, q);
            const float xni = (q < 3) ? comp4(ic, q + 1) : in4.x;
            const float xnj = (q < 3) ? comp4(jc, q + 1) : jn4.x;
            if (s < 31) {
#pragma unroll
                for (int k = 0; k < 8; ++k)
                    xnr[k] = rdlane(comp4(d4, k & 3), 2 * (s + 1) + (k >> 2));
            } else {
                // row t0+32 via uniform LDS broadcast (staged above)
#pragma unroll
                for (int k = 0; k < 8; ++k) xnr[k] = xT[k * TS + 32];
            }
            const float dxi = xni - xci;
            const float dxj = xnj - xcj;
            const float cpi = xci - x0i;
            const float cpj = xcj - x0j;
            (void)cpj;
            const float gg = dxj * fmaf(0.5f, dxi, cpi);          // dS2[ij] (FIXED)
            const float hh = dxj * fmaf(1.0f / 6.0f, dxi, 0.5f * cpi);
            const float gmh = gg - hh;
            S2f += gg;
#pragma unroll
            for (int k = 0; k < 8; ++k)
                A[k] = fmaf(gmh, xnr[k], fmaf(hh, xcr[k], A[k]));
#pragma unroll
            for (int k = 0; k < 8; ++k) xcr[k] = xnr[k];   // SSA rename, free
        }
        ic = in4;
        jc = jn4;
    }

    // Combine S2f across the 4 chunks (additive, exact).
    s_s2[w][l] = S2f;
    __syncthreads();
    const float S2T = s_s2[0][l] + s_s2[1][l] + s_s2[2][l] + s_s2[3][l];

    // Epilogue: out[o] = sum_l [ S2T*(W3.X127 + W2) - W3.A_tot ] + W1.S1 + bias
    // Each wave contributes -W3.A_w; wave 0 adds the S2T/S1 terms once.
    const float4 x7a = *reinterpret_cast<const float4*>(Xb + 1016);
    const float4 x7b = *reinterpret_cast<const float4*>(Xb + 1020);
#pragma unroll
    for (int o = 0; o < NOUT; ++o) {
        const float* wrow = W + o * SIG_DIM;
        const float4 w0 = *reinterpret_cast<const float4*>(wrow + 72 + l * 8);
        const float4 w1 = *reinterpret_cast<const float4*>(wrow + 72 + l * 8 + 4);
        float dA = w0.x * A[0];
        dA = fmaf(w0.y, A[1], dA); dA = fmaf(w0.z, A[2], dA);
        dA = fmaf(w0.w, A[3], dA); dA = fmaf(w1.x, A[4], dA);
        dA = fmaf(w1.y, A[5], dA); dA = fmaf(w1.z, A[6], dA);
        dA = fmaf(w1.w, A[7], dA);
        float part = -dA;
        if (w == 0) {
            float e = w0.x * x7a.x;
            e = fmaf(w0.y, x7a.y, e); e = fmaf(w0.z, x7a.z, e);
            e = fmaf(w0.w, x7a.w, e); e = fmaf(w1.x, x7b.x, e);
            e = fmaf(w1.y, x7b.y, e); e = fmaf(w1.z, x7b.z, e);
            e = fmaf(w1.w, x7b.w, e);
            part = fmaf(S2T, e + wrow[8 + l], part);
            if (i == 0) part = fmaf(s1jv, wrow[j], part);   // S1 contribution
        }
#pragma unroll
        for (int off = 32; off > 0; off >>= 1) part += __shfl_xor(part, off);
        if (l == o) s_part[w][o] = part;
    }
    __syncthreads();
    if (tid < NOUT)
        out[b * NOUT + tid] = s_part[0][tid] + s_part[1][tid] +
                              s_part[2][tid] + s_part[3][tid] + bias[tid];
}

extern "C" void kernel_launch(void* const* d_in, const int* in_sizes, int n_in,
                              void* d_out, int out_size, void* d_ws, size_t ws_size,
                              hipStream_t stream) {
    const float* X = (const float*)d_in[0];     // (2048, 128, 8)
    const float* W = (const float*)d_in[1];     // (10, 584)
    const float* bias = (const float*)d_in[2];  // (10,)
    float* out = (float*)d_out;                 // (2048, 10)
    sig_linear_kernel<<<dim3(2048), dim3(256), 0, stream>>>(X, W, bias, out);
}